// Round 1
// baseline (232.866 us; speedup 1.0000x reference)
//
#include <hip/hip_runtime.h>

#define LOG2E 1.4426950408889634f

typedef __attribute__((ext_vector_type(8))) short short8;
typedef __attribute__((ext_vector_type(4))) float f32x4;
using u32 = unsigned int;
using u16 = unsigned short;
using u64 = unsigned long long;

// ---------------------------------------------------------------------------
// Kernel P: pack adj (4096x4096 int32 0/1) into transposed bitmask.
// mask_t[wcol][row] (wcol = j>>5): per-row K-walk in k2 reads consecutive rows
// for a fixed word-column -> one 64B line serves 16 rows.
// ---------------------------------------------------------------------------
__global__ __launch_bounds__(256) void pack_mask_kernel(const int* __restrict__ adj,
                                                        u32* __restrict__ mask_t) {
    int wave = (blockIdx.x * 256 + threadIdx.x) >> 6;
    int lane = threadIdx.x & 63;
    // 4096 rows * 64 chunks of 64 j's
    for (int t = wave; t < 4096 * 64; t += 4096) {
        int row = t >> 6, cb = t & 63;
        int v = adj[(size_t)t * 64 + lane];   // flat = row*4096 + cb*64 + lane
        u64 bm = __ballot(v > 0);
        if (lane == 0) {
            mask_t[(size_t)(cb * 2 + 0) * 4096 + row] = (u32)bm;
            mask_t[(size_t)(cb * 2 + 1) * 4096 + row] = (u32)(bm >> 32);
        }
    }
}

// ---------------------------------------------------------------------------
// Kernel 1: h = x @ W (fp32, register-tiled 64x64 per WG, K staged in LDS),
// fused epilogue: s1 = h.a1, s2 = h.a2 (pre-scaled by log2e), h^T stored bf16.
// ---------------------------------------------------------------------------
__global__ __launch_bounds__(256) void k1_xw(const float* __restrict__ x,
                                             const float* __restrict__ W,
                                             const float* __restrict__ a,
                                             u16* __restrict__ h_t,
                                             float* __restrict__ s1p,
                                             float* __restrict__ s2p) {
    __shared__ float xs[64][36];   // stride 36 -> 16B-aligned float4 rows, conflict-free
    __shared__ float ws[32][64];
    const int b = blockIdx.y, rt = blockIdx.x;
    const int tid = threadIdx.x;
    const int rg = tid >> 4, cg = tid & 15;
    const int r0 = rg * 4, c0 = cg * 4;
    const float* xb = x + ((size_t)b * 4096 + (size_t)rt * 64) * 512;

    float acc[4][4];
#pragma unroll
    for (int i = 0; i < 4; i++)
#pragma unroll
        for (int j = 0; j < 4; j++) acc[i][j] = 0.f;

    float4 px[2], pw[2];
#pragma unroll
    for (int it = 0; it < 2; it++) {     // prefetch k-tile 0
        int c = tid + it * 256;
        px[it] = *(const float4*)(xb + (size_t)(c >> 3) * 512 + ((c & 7) << 2));
        pw[it] = *(const float4*)(W + (size_t)(c >> 4) * 64 + ((c & 15) << 2));
    }
    for (int kt = 0; kt < 16; kt++) {
        __syncthreads();
#pragma unroll
        for (int it = 0; it < 2; it++) {
            int c = tid + it * 256;
            *(float4*)&xs[c >> 3][(c & 7) << 2] = px[it];
            *(float4*)&ws[c >> 4][(c & 15) << 2] = pw[it];
        }
        __syncthreads();
        if (kt < 15) {                   // prefetch next tile during compute
            int k0 = (kt + 1) * 32;
#pragma unroll
            for (int it = 0; it < 2; it++) {
                int c = tid + it * 256;
                px[it] = *(const float4*)(xb + (size_t)(c >> 3) * 512 + k0 + ((c & 7) << 2));
                pw[it] = *(const float4*)(W + (size_t)(k0 + (c >> 4)) * 64 + ((c & 15) << 2));
            }
        }
#pragma unroll
        for (int k4 = 0; k4 < 32; k4 += 4) {
            float4 xv[4], wv[4];
#pragma unroll
            for (int rr = 0; rr < 4; rr++) xv[rr] = *(const float4*)&xs[r0 + rr][k4];
#pragma unroll
            for (int kk = 0; kk < 4; kk++) wv[kk] = *(const float4*)&ws[k4 + kk][c0];
#pragma unroll
            for (int rr = 0; rr < 4; rr++)
#pragma unroll
                for (int kk = 0; kk < 4; kk++) {
                    const float xvv = ((const float*)&xv[rr])[kk];
#pragma unroll
                    for (int cc = 0; cc < 4; cc++)
                        acc[rr][cc] = fmaf(xvv, ((const float*)&wv[kk])[cc], acc[rr][cc]);
                }
        }
    }
    // s1/s2 partials over this thread's 4 cols, reduce across the 16 col-groups
    float s1v[4], s2v[4];
#pragma unroll
    for (int rr = 0; rr < 4; rr++) { s1v[rr] = 0.f; s2v[rr] = 0.f; }
#pragma unroll
    for (int cc = 0; cc < 4; cc++) {
        float a1 = a[c0 + cc], a2 = a[64 + c0 + cc];
#pragma unroll
        for (int rr = 0; rr < 4; rr++) {
            s1v[rr] = fmaf(acc[rr][cc], a1, s1v[rr]);
            s2v[rr] = fmaf(acc[rr][cc], a2, s2v[rr]);
        }
    }
#pragma unroll
    for (int d = 1; d < 16; d <<= 1) {
#pragma unroll
        for (int rr = 0; rr < 4; rr++) {
            s1v[rr] += __shfl_xor(s1v[rr], d);
            s2v[rr] += __shfl_xor(s2v[rr], d);
        }
    }
    if (cg == 0) {
#pragma unroll
        for (int rr = 0; rr < 4; rr++) {
            int row = rt * 64 + r0 + rr;
            s1p[b * 4096 + row] = s1v[rr] * LOG2E;   // pre-scale: exp(x)=exp2(x*log2e)
            s2p[b * 4096 + row] = s2v[rr] * LOG2E;
        }
    }
    // h^T bf16 (round-half-up): h_t[b][o][n]
#pragma unroll
    for (int cc = 0; cc < 4; cc++) {
        u32 b0 = __float_as_uint(acc[0][cc]) + 0x8000u;
        u32 b1 = __float_as_uint(acc[1][cc]) + 0x8000u;
        u32 b2 = __float_as_uint(acc[2][cc]) + 0x8000u;
        u32 b3 = __float_as_uint(acc[3][cc]) + 0x8000u;
        uint2 u;
        u.x = (b0 >> 16) | (b1 & 0xffff0000u);
        u.y = (b2 >> 16) | (b3 & 0xffff0000u);
        *(uint2*)(h_t + ((size_t)(b * 64 + c0 + cc)) * 4096 + rt * 64 + r0) = u;
    }
}

// ---------------------------------------------------------------------------
// Kernel 2: fused masked-softmax-numerator GEMM.
// WG = 4 waves, 64 attention rows, one j-segment (K-split S).
// Per wave: 16 rows x 64 out-cols via 4x mfma_f32_16x16x32_bf16; A-frag (the
// unnormalized attention weights) built in-register from s1+s2+mask bits;
// denominator = sum of the SAME truncated-bf16 weights (bias cancels).
// ---------------------------------------------------------------------------
__global__ __launch_bounds__(256, 4) void k2_attn(const u16* __restrict__ h_t,
                                                  const u32* __restrict__ mask_t,
                                                  const float* __restrict__ s1p,
                                                  const float* __restrict__ s2p,
                                                  float* __restrict__ part,
                                                  float* __restrict__ lp,
                                                  int JSEG) {
    extern __shared__ char smem[];
    u16* hB = (u16*)smem;                  // 64(o) x 64(j) bf16, xor-swizzled, 8 KB
    float* s2l = (float*)(smem + 8192);    // JSEG floats
    const int b = blockIdx.y, seg = blockIdx.z, rb = blockIdx.x;
    const int tid = threadIdx.x, wave = tid >> 6, lane = tid & 63;
    const int m = lane & 15, quad = lane >> 4;
    const int row = rb * 64 + wave * 16 + m;
    const int jstart = seg * JSEG;
    const float t1 = s1p[b * 4096 + row];
    for (int t = tid; t < (JSEG >> 2); t += 256)
        ((float4*)s2l)[t] = ((const float4*)(s2p + b * 4096 + jstart))[t];
    const u16* hsrc = h_t + (size_t)b * 64 * 4096 + jstart;

    f32x4 acc[4];
#pragma unroll
    for (int ot = 0; ot < 4; ot++) acc[ot] = (f32x4){0.f, 0.f, 0.f, 0.f};
    float lsum = 0.f;

    const int cj = tid & 7;                // this thread's 16B chunk column
    uint4 pf[2];
#pragma unroll
    for (int it = 0; it < 2; it++) {       // prefetch j-tile 0
        int o = (tid >> 3) + it * 32;
        pf[it] = *(const uint4*)(hsrc + (size_t)o * 4096 + (cj << 3));
    }
    for (int jt = 0; jt < JSEG; jt += 64) {
        __syncthreads();
#pragma unroll
        for (int it = 0; it < 2; it++) {   // LDS write, xor-swizzle jc^(o&7)
            int o = (tid >> 3) + it * 32;
            *(uint4*)(hB + (size_t)o * 64 + ((cj ^ (o & 7)) << 3)) = pf[it];
        }
        __syncthreads();
        if (jt + 64 < JSEG) {
#pragma unroll
            for (int it = 0; it < 2; it++) {
                int o = (tid >> 3) + it * 32;
                pf[it] = *(const uint4*)(hsrc + (size_t)o * 4096 + (jt + 64) + (cj << 3));
            }
        }
#pragma unroll
        for (int ks = 0; ks < 2; ks++) {
            const int j0 = jt + ks * 32;
            const u32 mw = mask_t[(size_t)((jstart + j0) >> 5) * 4096 + row];
            const u32 mb = (mw >> (quad * 8)) & 0xffu;
            const float4 sa = *(const float4*)&s2l[j0 + quad * 8];
            const float4 sb = *(const float4*)&s2l[j0 + quad * 8 + 4];
            const float sv[8] = {sa.x, sa.y, sa.z, sa.w, sb.x, sb.y, sb.z, sb.w};
            union { u32 u[4]; short8 v; } af;
#pragma unroll
            for (int p = 0; p < 4; p++) {
                float t0 = t1 + sv[2 * p];
                float u0 = fmaxf(t0, 0.2f * t0);              // leaky-relu (scaled domain)
                u0 = (mb & (1u << (2 * p))) ? u0 : -1e30f;    // masked -> exp2 = 0
                float w0 = __builtin_amdgcn_exp2f(u0);
                float t2 = t1 + sv[2 * p + 1];
                float u2 = fmaxf(t2, 0.2f * t2);
                u2 = (mb & (2u << (2 * p))) ? u2 : -1e30f;
                float w1 = __builtin_amdgcn_exp2f(u2);
                u32 c0b = __float_as_uint(w0) & 0xffff0000u;  // truncate to bf16
                u32 c1b = __float_as_uint(w1) & 0xffff0000u;
                lsum += __uint_as_float(c0b) + __uint_as_float(c1b);  // same values as numerator
                af.u[p] = (c0b >> 16) | c1b;
            }
            const int jc = ks * 4 + quad;
#pragma unroll
            for (int ot = 0; ot < 4; ot++) {
                const int o = ot * 16 + m;
                short8 bf = *(const short8*)(hB + (size_t)o * 64 + ((jc ^ (o & 7)) << 3));
                acc[ot] = __builtin_amdgcn_mfma_f32_16x16x32_bf16(af.v, bf, acc[ot], 0, 0, 0);
            }
        }
    }
    // store fp32 partials; C/D layout: col=lane&15, row=quad*4+reg
    float* pb = part + (((size_t)(seg * 4 + b) * 4096) + rb * 64 + wave * 16) * 64;
#pragma unroll
    for (int ot = 0; ot < 4; ot++)
#pragma unroll
        for (int r = 0; r < 4; r++)
            pb[(quad * 4 + r) * 64 + ot * 16 + m] = acc[ot][r];
    lp[((size_t)(seg * 4 + b) * 4096 + row) * 4 + quad] = lsum;
}

// ---------------------------------------------------------------------------
// Kernel 3: combine K-split partials, normalize, elu.
// ---------------------------------------------------------------------------
__global__ __launch_bounds__(256) void k3_fin(const float* __restrict__ part,
                                              const float* __restrict__ lp,
                                              float* __restrict__ out, int S) {
    int idx = blockIdx.x * 256 + threadIdx.x;    // 262144 = 4*4096*16
    int o4 = (idx & 15) << 2;
    int bi = idx >> 4;
    float p0 = 0.f, p1 = 0.f, p2 = 0.f, p3 = 0.f, l = 0.f;
    for (int s = 0; s < S; s++) {
        const float4 v = *(const float4*)&part[((size_t)s * 16384 + bi) * 64 + o4];
        p0 += v.x; p1 += v.y; p2 += v.z; p3 += v.w;
        const float* lpp = &lp[((size_t)s * 16384 + bi) * 4];
        l += (lpp[0] + lpp[1]) + (lpp[2] + lpp[3]);
    }
    float rl = 1.f / l;
    p0 *= rl; p1 *= rl; p2 *= rl; p3 *= rl;
    float4 o;
    o.x = p0 > 0.f ? p0 : __builtin_amdgcn_exp2f(p0 * LOG2E) - 1.f;
    o.y = p1 > 0.f ? p1 : __builtin_amdgcn_exp2f(p1 * LOG2E) - 1.f;
    o.z = p2 > 0.f ? p2 : __builtin_amdgcn_exp2f(p2 * LOG2E) - 1.f;
    o.w = p3 > 0.f ? p3 : __builtin_amdgcn_exp2f(p3 * LOG2E) - 1.f;
    *(float4*)&out[(size_t)bi * 64 + o4] = o;
}

// ---------------------------------------------------------------------------
extern "C" void kernel_launch(void* const* d_in, const int* in_sizes, int n_in,
                              void* d_out, int out_size, void* d_ws, size_t ws_size,
                              hipStream_t stream) {
    const float* x  = (const float*)d_in[0];
    const int* adj  = (const int*)d_in[1];
    const float* W  = (const float*)d_in[2];
    const float* a  = (const float*)d_in[3];
    float* out = (float*)d_out;
    char* ws = (char*)d_ws;

    // workspace layout
    u16* h_t   = (u16*)ws;                         // 4*64*4096*2       = 2 MB
    u32* maskt = (u32*)(ws + (2 << 20));           // 128*4096*4        = 2 MB
    float* s1p = (float*)(ws + (4 << 20));         // 64 KB
    float* s2p = s1p + 16384;                      // 64 KB
    float* lp  = s2p + 16384;                      // S*4*4096*4*4      = S*256 KB
    size_t base = (4u << 20) + 2 * 65536;
    int S = 4;                                     // K-split (occupancy: 4 waves/SIMD)
    while (S > 1 && base + (size_t)S * (262144 + 4194304) > ws_size) S >>= 1;
    float* part = (float*)(ws + base + (size_t)S * 262144);   // S*4 MB
    int JSEG = 4096 / S;

    pack_mask_kernel<<<1024, 256, 0, stream>>>(adj, maskt);
    k1_xw<<<dim3(64, 4), 256, 0, stream>>>(x, W, a, h_t, s1p, s2p);
    k2_attn<<<dim3(64, 4, S), 256, 8192 + JSEG * 4, stream>>>(h_t, maskt, s1p, s2p,
                                                              part, lp, JSEG);
    k3_fin<<<1024, 256, 0, stream>>>(part, lp, out, S);
}

// Round 2
// 228.024 us; speedup vs baseline: 1.0212x; 1.0212x over previous
//
#include <hip/hip_runtime.h>

#define LOG2E 1.4426950408889634f

typedef __attribute__((ext_vector_type(8))) short short8;
typedef __attribute__((ext_vector_type(4))) float f32x4;
using u32 = unsigned int;
using u16 = unsigned short;
using u64 = unsigned long long;

// ---------------------------------------------------------------------------
// Kernel P: pack adj (4096x4096 int32 0/1) into transposed bitmask.
// ---------------------------------------------------------------------------
__global__ __launch_bounds__(256) void pack_mask_kernel(const int* __restrict__ adj,
                                                        u32* __restrict__ mask_t) {
    int wave = (blockIdx.x * 256 + threadIdx.x) >> 6;
    int lane = threadIdx.x & 63;
    for (int t = wave; t < 4096 * 64; t += 4096) {
        int row = t >> 6, cb = t & 63;
        int v = adj[(size_t)t * 64 + lane];
        u64 bm = __ballot(v > 0);
        if (lane == 0) {
            mask_t[(size_t)(cb * 2 + 0) * 4096 + row] = (u32)bm;
            mask_t[(size_t)(cb * 2 + 1) * 4096 + row] = (u32)(bm >> 32);
        }
    }
}

// ---------------------------------------------------------------------------
// Kernel 1: h-partial = x @ W over one K-segment (K-split KS for occupancy:
// grid (64,4,KS) = 1024 WGs -> 4 waves/SIMD so LDS latency hides under VALU).
// fp32 partials land in the (not-yet-used) k2 part buffer.
// ---------------------------------------------------------------------------
__global__ __launch_bounds__(256) void k1_xw(const float* __restrict__ x,
                                             const float* __restrict__ W,
                                             float* __restrict__ ph,
                                             int TILES) {
    __shared__ float xs[64][36];   // stride 36 -> 16B-aligned float4 rows, conflict-free
    __shared__ float ws[32][64];
    const int b = blockIdx.y, rt = blockIdx.x, ks = blockIdx.z;
    const int tid = threadIdx.x;
    const int rg = tid >> 4, cg = tid & 15;
    const int r0 = rg * 4, c0 = cg * 4;
    const int kt0 = ks * TILES;
    const float* xb = x + ((size_t)b * 4096 + (size_t)rt * 64) * 512;

    float acc[4][4];
#pragma unroll
    for (int i = 0; i < 4; i++)
#pragma unroll
        for (int j = 0; j < 4; j++) acc[i][j] = 0.f;

    float4 px[2], pw[2];
#pragma unroll
    for (int it = 0; it < 2; it++) {     // prefetch first k-tile of this segment
        int c = tid + it * 256;
        px[it] = *(const float4*)(xb + (size_t)(c >> 3) * 512 + kt0 * 32 + ((c & 7) << 2));
        pw[it] = *(const float4*)(W + (size_t)(kt0 * 32 + (c >> 4)) * 64 + ((c & 15) << 2));
    }
    for (int kt = kt0; kt < kt0 + TILES; kt++) {
        __syncthreads();
#pragma unroll
        for (int it = 0; it < 2; it++) {
            int c = tid + it * 256;
            *(float4*)&xs[c >> 3][(c & 7) << 2] = px[it];
            *(float4*)&ws[c >> 4][(c & 15) << 2] = pw[it];
        }
        __syncthreads();
        if (kt < kt0 + TILES - 1) {
            int k0 = (kt + 1) * 32;
#pragma unroll
            for (int it = 0; it < 2; it++) {
                int c = tid + it * 256;
                px[it] = *(const float4*)(xb + (size_t)(c >> 3) * 512 + k0 + ((c & 7) << 2));
                pw[it] = *(const float4*)(W + (size_t)(k0 + (c >> 4)) * 64 + ((c & 15) << 2));
            }
        }
#pragma unroll
        for (int k4 = 0; k4 < 32; k4 += 4) {
            float4 xv[4], wv[4];
#pragma unroll
            for (int rr = 0; rr < 4; rr++) xv[rr] = *(const float4*)&xs[r0 + rr][k4];
#pragma unroll
            for (int kk = 0; kk < 4; kk++) wv[kk] = *(const float4*)&ws[k4 + kk][c0];
#pragma unroll
            for (int rr = 0; rr < 4; rr++)
#pragma unroll
                for (int kk = 0; kk < 4; kk++) {
                    const float xvv = ((const float*)&xv[rr])[kk];
#pragma unroll
                    for (int cc = 0; cc < 4; cc++)
                        acc[rr][cc] = fmaf(xvv, ((const float*)&wv[kk])[cc], acc[rr][cc]);
                }
        }
    }
    // store fp32 partial tile (coalesced float4 rows)
    float* pb = ph + (((size_t)(ks * 4 + b) * 4096) + rt * 64) * 64;
#pragma unroll
    for (int rr = 0; rr < 4; rr++)
        *(float4*)&pb[(size_t)(r0 + rr) * 64 + c0] = *(float4*)&acc[rr][0];
}

// ---------------------------------------------------------------------------
// Kernel 1c: sum K-split partials; fused epilogue: s1 = h.a1, s2 = h.a2
// (pre-scaled by log2e), h^T stored bf16.
// ---------------------------------------------------------------------------
__global__ __launch_bounds__(256) void k1c_fin(const float* __restrict__ ph,
                                               const float* __restrict__ a,
                                               u16* __restrict__ h_t,
                                               float* __restrict__ s1p,
                                               float* __restrict__ s2p,
                                               int KS) {
    const int b = blockIdx.y, rt = blockIdx.x;
    const int tid = threadIdx.x;
    const int rg = tid >> 4, cg = tid & 15;
    const int r0 = rg * 4, c0 = cg * 4;

    float acc[4][4];
#pragma unroll
    for (int i = 0; i < 4; i++)
#pragma unroll
        for (int j = 0; j < 4; j++) acc[i][j] = 0.f;
    for (int s = 0; s < KS; s++) {
        const float* pb = ph + (((size_t)(s * 4 + b) * 4096) + rt * 64) * 64;
#pragma unroll
        for (int rr = 0; rr < 4; rr++) {
            float4 v = *(const float4*)&pb[(size_t)(r0 + rr) * 64 + c0];
            acc[rr][0] += v.x; acc[rr][1] += v.y; acc[rr][2] += v.z; acc[rr][3] += v.w;
        }
    }
    // s1/s2 partials over this thread's 4 cols, reduce across the 16 col-groups
    float s1v[4], s2v[4];
#pragma unroll
    for (int rr = 0; rr < 4; rr++) { s1v[rr] = 0.f; s2v[rr] = 0.f; }
#pragma unroll
    for (int cc = 0; cc < 4; cc++) {
        float a1 = a[c0 + cc], a2 = a[64 + c0 + cc];
#pragma unroll
        for (int rr = 0; rr < 4; rr++) {
            s1v[rr] = fmaf(acc[rr][cc], a1, s1v[rr]);
            s2v[rr] = fmaf(acc[rr][cc], a2, s2v[rr]);
        }
    }
#pragma unroll
    for (int d = 1; d < 16; d <<= 1) {
#pragma unroll
        for (int rr = 0; rr < 4; rr++) {
            s1v[rr] += __shfl_xor(s1v[rr], d);
            s2v[rr] += __shfl_xor(s2v[rr], d);
        }
    }
    if (cg == 0) {
#pragma unroll
        for (int rr = 0; rr < 4; rr++) {
            int row = rt * 64 + r0 + rr;
            s1p[b * 4096 + row] = s1v[rr] * LOG2E;
            s2p[b * 4096 + row] = s2v[rr] * LOG2E;
        }
    }
    // h^T bf16 (round-half-up): h_t[b][o][n]
#pragma unroll
    for (int cc = 0; cc < 4; cc++) {
        u32 b0 = __float_as_uint(acc[0][cc]) + 0x8000u;
        u32 b1 = __float_as_uint(acc[1][cc]) + 0x8000u;
        u32 b2 = __float_as_uint(acc[2][cc]) + 0x8000u;
        u32 b3 = __float_as_uint(acc[3][cc]) + 0x8000u;
        uint2 u;
        u.x = (b0 >> 16) | (b1 & 0xffff0000u);
        u.y = (b2 >> 16) | (b3 & 0xffff0000u);
        *(uint2*)(h_t + ((size_t)(b * 64 + c0 + cc)) * 4096 + rt * 64 + r0) = u;
    }
}

// ---------------------------------------------------------------------------
// Kernel 2: fused masked-softmax-numerator GEMM (unchanged this round).
// ---------------------------------------------------------------------------
__global__ __launch_bounds__(256, 4) void k2_attn(const u16* __restrict__ h_t,
                                                  const u32* __restrict__ mask_t,
                                                  const float* __restrict__ s1p,
                                                  const float* __restrict__ s2p,
                                                  float* __restrict__ part,
                                                  float* __restrict__ lp,
                                                  int JSEG) {
    extern __shared__ char smem[];
    u16* hB = (u16*)smem;                  // 64(o) x 64(j) bf16, xor-swizzled, 8 KB
    float* s2l = (float*)(smem + 8192);    // JSEG floats
    const int b = blockIdx.y, seg = blockIdx.z, rb = blockIdx.x;
    const int tid = threadIdx.x, wave = tid >> 6, lane = tid & 63;
    const int m = lane & 15, quad = lane >> 4;
    const int row = rb * 64 + wave * 16 + m;
    const int jstart = seg * JSEG;
    const float t1 = s1p[b * 4096 + row];
    for (int t = tid; t < (JSEG >> 2); t += 256)
        ((float4*)s2l)[t] = ((const float4*)(s2p + b * 4096 + jstart))[t];
    const u16* hsrc = h_t + (size_t)b * 64 * 4096 + jstart;

    f32x4 acc[4];
#pragma unroll
    for (int ot = 0; ot < 4; ot++) acc[ot] = (f32x4){0.f, 0.f, 0.f, 0.f};
    float lsum = 0.f;

    const int cj = tid & 7;
    uint4 pf[2];
#pragma unroll
    for (int it = 0; it < 2; it++) {
        int o = (tid >> 3) + it * 32;
        pf[it] = *(const uint4*)(hsrc + (size_t)o * 4096 + (cj << 3));
    }
    for (int jt = 0; jt < JSEG; jt += 64) {
        __syncthreads();
#pragma unroll
        for (int it = 0; it < 2; it++) {
            int o = (tid >> 3) + it * 32;
            *(uint4*)(hB + (size_t)o * 64 + ((cj ^ (o & 7)) << 3)) = pf[it];
        }
        __syncthreads();
        if (jt + 64 < JSEG) {
#pragma unroll
            for (int it = 0; it < 2; it++) {
                int o = (tid >> 3) + it * 32;
                pf[it] = *(const uint4*)(hsrc + (size_t)o * 4096 + (jt + 64) + (cj << 3));
            }
        }
#pragma unroll
        for (int ks = 0; ks < 2; ks++) {
            const int j0 = jt + ks * 32;
            const u32 mw = mask_t[(size_t)((jstart + j0) >> 5) * 4096 + row];
            const u32 mb = (mw >> (quad * 8)) & 0xffu;
            const float4 sa = *(const float4*)&s2l[j0 + quad * 8];
            const float4 sb = *(const float4*)&s2l[j0 + quad * 8 + 4];
            const float sv[8] = {sa.x, sa.y, sa.z, sa.w, sb.x, sb.y, sb.z, sb.w};
            union { u32 u[4]; short8 v; } af;
#pragma unroll
            for (int p = 0; p < 4; p++) {
                float t0 = t1 + sv[2 * p];
                float u0 = fmaxf(t0, 0.2f * t0);
                u0 = (mb & (1u << (2 * p))) ? u0 : -1e30f;
                float w0 = __builtin_amdgcn_exp2f(u0);
                float t2 = t1 + sv[2 * p + 1];
                float u2 = fmaxf(t2, 0.2f * t2);
                u2 = (mb & (2u << (2 * p))) ? u2 : -1e30f;
                float w1 = __builtin_amdgcn_exp2f(u2);
                u32 c0b = __float_as_uint(w0) & 0xffff0000u;
                u32 c1b = __float_as_uint(w1) & 0xffff0000u;
                lsum += __uint_as_float(c0b) + __uint_as_float(c1b);
                af.u[p] = (c0b >> 16) | c1b;
            }
            const int jc = ks * 4 + quad;
#pragma unroll
            for (int ot = 0; ot < 4; ot++) {
                const int o = ot * 16 + m;
                short8 bf = *(const short8*)(hB + (size_t)o * 64 + ((jc ^ (o & 7)) << 3));
                acc[ot] = __builtin_amdgcn_mfma_f32_16x16x32_bf16(af.v, bf, acc[ot], 0, 0, 0);
            }
        }
    }
    float* pb = part + (((size_t)(seg * 4 + b) * 4096) + rb * 64 + wave * 16) * 64;
#pragma unroll
    for (int ot = 0; ot < 4; ot++)
#pragma unroll
        for (int r = 0; r < 4; r++)
            pb[(quad * 4 + r) * 64 + ot * 16 + m] = acc[ot][r];
    lp[((size_t)(seg * 4 + b) * 4096 + row) * 4 + quad] = lsum;
}

// ---------------------------------------------------------------------------
// Kernel 3: combine K-split partials, normalize, elu.
// ---------------------------------------------------------------------------
__global__ __launch_bounds__(256) void k3_fin(const float* __restrict__ part,
                                              const float* __restrict__ lp,
                                              float* __restrict__ out, int S) {
    int idx = blockIdx.x * 256 + threadIdx.x;    // 262144 = 4*4096*16
    int o4 = (idx & 15) << 2;
    int bi = idx >> 4;
    float p0 = 0.f, p1 = 0.f, p2 = 0.f, p3 = 0.f, l = 0.f;
    for (int s = 0; s < S; s++) {
        const float4 v = *(const float4*)&part[((size_t)s * 16384 + bi) * 64 + o4];
        p0 += v.x; p1 += v.y; p2 += v.z; p3 += v.w;
        const float* lpp = &lp[((size_t)s * 16384 + bi) * 4];
        l += (lpp[0] + lpp[1]) + (lpp[2] + lpp[3]);
    }
    float rl = 1.f / l;
    p0 *= rl; p1 *= rl; p2 *= rl; p3 *= rl;
    float4 o;
    o.x = p0 > 0.f ? p0 : __builtin_amdgcn_exp2f(p0 * LOG2E) - 1.f;
    o.y = p1 > 0.f ? p1 : __builtin_amdgcn_exp2f(p1 * LOG2E) - 1.f;
    o.z = p2 > 0.f ? p2 : __builtin_amdgcn_exp2f(p2 * LOG2E) - 1.f;
    o.w = p3 > 0.f ? p3 : __builtin_amdgcn_exp2f(p3 * LOG2E) - 1.f;
    *(float4*)&out[(size_t)bi * 64 + o4] = o;
}

// ---------------------------------------------------------------------------
extern "C" void kernel_launch(void* const* d_in, const int* in_sizes, int n_in,
                              void* d_out, int out_size, void* d_ws, size_t ws_size,
                              hipStream_t stream) {
    const float* x  = (const float*)d_in[0];
    const int* adj  = (const int*)d_in[1];
    const float* W  = (const float*)d_in[2];
    const float* a  = (const float*)d_in[3];
    float* out = (float*)d_out;
    char* ws = (char*)d_ws;

    // workspace layout
    u16* h_t   = (u16*)ws;                         // 4*64*4096*2       = 2 MB
    u32* maskt = (u32*)(ws + (2 << 20));           // 128*4096*4        = 2 MB
    float* s1p = (float*)(ws + (4 << 20));         // 64 KB
    float* s2p = s1p + 16384;                      // 64 KB
    float* lp  = s2p + 16384;                      // S*4*4096*4*4      = S*256 KB
    size_t base = (4u << 20) + 2 * 65536;
    int S = 4;                                     // k2 j-split
    while (S > 1 && base + (size_t)S * (262144 + 4194304) > ws_size) S >>= 1;
    float* part = (float*)(ws + base + (size_t)S * 262144);   // S*4 MB
    int JSEG = 4096 / S;
    // k1 K-split partials alias the part buffer (free until k2 writes it)
    int KS = 4;
    while (KS > 1 && base + (size_t)S * 262144 + (size_t)KS * 4194304 > ws_size) KS >>= 1;

    pack_mask_kernel<<<1024, 256, 0, stream>>>(adj, maskt);
    k1_xw<<<dim3(64, 4, KS), 256, 0, stream>>>(x, W, part, 16 / KS);
    k1c_fin<<<dim3(64, 4), 256, 0, stream>>>(part, a, h_t, s1p, s2p, KS);
    k2_attn<<<dim3(64, 4, S), 256, 8192 + JSEG * 4, stream>>>(h_t, maskt, s1p, s2p,
                                                              part, lp, JSEG);
    k3_fin<<<1024, 256, 0, stream>>>(part, lp, out, S);
}